// Round 4
// baseline (506.921 us; speedup 1.0000x reference)
//
#include <hip/hip_runtime.h>
#include <math.h>

// n is fixed by the problem: angles has n(n-1)/2 = 2016 -> n = 64.
#define N 64
#define NPAIRS (N * (N - 1) / 2)  // 2016

// ---------------------------------------------------------------------------
// Kernel 1: build R^T (scaled by mus) from the Givens angle sequence.
// ONE wave. The working matrix lives in LDS (column j per lane:
// W[i*64 + lane]), so the rotation chain is a tiny RUNTIME loop
// (~15 instructions total) instead of 16k instructions of unrolled
// straight-line code. Rounds 0-3 showed every fully-unrolled variant is
// instruction-fetch-bound at ~150-185 us (130 KB of once-executed code
// streamed through one CU's L1I); this version's code footprint is ~1 KB.
// Per inner step: 1 uniform ds_read_b64 (cs, broadcast) + 1 ds_read_b32 +
// 1 ds_write_b32 (both stride-1 across lanes -> 2-way aliasing, free) +
// 2 FMA. Serial chain: 2016 x ~4cy fma ~ 3.4 us; LDS issue ~ 15 us.
// Output layout: RT[j*64 + i] = mus[i] * R[i][j]  (same as verified rounds).
// ---------------------------------------------------------------------------
__global__ __launch_bounds__(64) void build_r_kernel(
    const float* __restrict__ angles, const float* __restrict__ mus,
    float* __restrict__ RT) {
  __shared__ float2 cs[NPAIRS];  // 16128 B
  __shared__ float W[N * N];     // 16384 B, W[i*64 + j] = R[i][j]

  const int lane = threadIdx.x;

  // Parallel sincos: each lane handles ~32 angles.
  for (int k = lane; k < NPAIRS; k += 64) {
    float s, c;
    sincosf(angles[k], &s, &c);
    cs[k] = make_float2(c, s);
  }

  // Identity: lane owns column `lane`.
  for (int i = 0; i < N; ++i) W[i * N + lane] = (i == lane) ? 1.0f : 0.0f;
  __syncthreads();

  // Sequential Givens chain, same order as np.triu_indices (row-major).
  // R[t] = c*R[t] - s*R[b]; R[b] = s*R[t_old] + c*R[b]
  int k = 0;
  for (int t = 0; t < N - 1; ++t) {
    float vt = W[t * N + lane];  // row-t component of this lane's column
    for (int b = t + 1; b < N; ++b) {
      const float2 p = cs[k++];          // uniform -> LDS broadcast
      const float vb = W[b * N + lane];  // stride-1 across lanes
      W[b * N + lane] = fmaf(p.y, vt, p.x * vb);  // uses old vt
      vt = fmaf(p.x, vt, -p.y * vb);              // uses old vb
    }
    W[t * N + lane] = vt;
  }
  __syncthreads();

  // RT[j][i] = mus[i] * R[i][j]; lane = j. 16 KB total, bandwidth-trivial.
  for (int i = 0; i < N; ++i) {
    RT[lane * N + i] = mus[i] * W[i * N + lane];
  }
}

// ---------------------------------------------------------------------------
// Kernel 2: out[i][j] = sum_k R[i][k] * X[k][j].
// EXACT round-0 proven structure (apply ~ 145 us): one column j per thread,
// 64 fp32 accumulators in VGPRs (VGPR ~68, 7 waves/SIMD). RT reads are
// wave-uniform -> scalar s_load_dwordx4 on the free scalar pipe. X loads /
// out stores: plain, lane-consecutive -> fully coalesced 256 B / wave.
// (NT hints removed: unproven delta vs the round-0 measurement.)
// ---------------------------------------------------------------------------
__global__ __launch_bounds__(256) void apply_r_kernel(
    const float* __restrict__ X, const float* __restrict__ RT,
    float* __restrict__ out, int m) {
  const int j = blockIdx.x * 256 + threadIdx.x;
  if (j >= m) return;

  float acc[N];
#pragma unroll
  for (int i = 0; i < N; ++i) acc[i] = 0.0f;

  const float* xp = X + j;
#pragma unroll 4
  for (int k = 0; k < N; ++k) {
    const float x = xp[(size_t)k * m];
    const float4* r4 = (const float4*)(RT + k * N);
#pragma unroll
    for (int ii = 0; ii < N / 4; ++ii) {
      float4 r = r4[ii];
      acc[ii * 4 + 0] = fmaf(r.x, x, acc[ii * 4 + 0]);
      acc[ii * 4 + 1] = fmaf(r.y, x, acc[ii * 4 + 1]);
      acc[ii * 4 + 2] = fmaf(r.z, x, acc[ii * 4 + 2]);
      acc[ii * 4 + 3] = fmaf(r.w, x, acc[ii * 4 + 3]);
    }
  }

#pragma unroll
  for (int i = 0; i < N; ++i) {
    out[(size_t)i * m + j] = acc[i];
  }
}

extern "C" void kernel_launch(void* const* d_in, const int* in_sizes, int n_in,
                              void* d_out, int out_size, void* d_ws,
                              size_t ws_size, hipStream_t stream) {
  const float* X = (const float*)d_in[0];       // 64 x m fp32
  const float* angles = (const float*)d_in[1];  // 2016 fp32
  const float* mus = (const float*)d_in[2];     // 64 fp32
  float* out = (float*)d_out;                   // 64 x m fp32
  float* RT = (float*)d_ws;                     // 64*64 fp32 scratch (16 KB)

  const int m = in_sizes[0] / N;

  build_r_kernel<<<1, 64, 0, stream>>>(angles, mus, RT);

  const int blocks = (m + 255) / 256;
  apply_r_kernel<<<blocks, 256, 0, stream>>>(X, RT, out, m);
}